// Round 6
// baseline (465.065 us; speedup 1.0000x reference)
//
#include <hip/hip_runtime.h>
#include <hip/hip_bf16.h>
#include <math.h>

#define HEADS 8
#define HEAD_DIM 32
#define DIM 256
#define MLP_DIM 1024
#define NTOK 4096
#define BATCH 8
#define M_TOK (BATCH*NTOK)
#define CELL_DIM 15
#define PE_IN 3
#define UPD 12
#define HME ((size_t)M_TOK*32)   // elements per head-plane [tok][32]

typedef __attribute__((ext_vector_type(8))) short bf16x8;
typedef __attribute__((ext_vector_type(4))) float f32x4;

static __device__ __forceinline__ float bf2f(unsigned short u) {
    return __uint_as_float(((unsigned int)u) << 16);
}
static __device__ __forceinline__ unsigned short f2bf(float f) {
    __hip_bfloat16 h = __float2bfloat16(f);
    union { __hip_bfloat16 h; unsigned short u; } cv; cv.h = h; return cv.u;
}
static __device__ __forceinline__ void gload_lds16(const unsigned short* g, unsigned short* l) {
    __builtin_amdgcn_global_load_lds(
        (const __attribute__((address_space(1))) void*)g,
        (__attribute__((address_space(3))) void*)l, 16, 0, 0);
}
static __device__ __forceinline__ float gelu_exact(float v) {
    return v * 0.5f * (1.f + erff(v * 0.70710678118f));
}

// embed + fused LN1[0]: x = cells@We + be + pe ; y = LN(x)
__global__ __launch_bounds__(256) void k_embed(const float* __restrict__ cells,
        const float* __restrict__ We, const float* __restrict__ be,
        const float* __restrict__ g, const float* __restrict__ bln,
        float* __restrict__ x, unsigned short* __restrict__ y) {
    __shared__ float red[8];
    int tok = blockIdx.x;
    int d = threadIdx.x;
    int b = tok >> 12, n = tok & 4095;
    const float* cb = cells + (size_t)b * CELL_DIM * NTOK + n;
    float acc = 0.f;
#pragma unroll
    for (int c = 0; c < CELL_DIM; ++c)
        acc += cb[c * NTOK] * We[c * DIM + d];
    int i = d >> 1;
    float freq = expf(-logf(10000.f) * (float)(2 * i) / (float)DIM);
    float ph = (float)n * freq;
    float pe = (d & 1) ? cosf(ph) : sinf(ph);
    float v = acc + be[d] + pe;
    x[(size_t)tok * DIM + d] = v;
    float s = v, ss = v * v;
#pragma unroll
    for (int off = 32; off; off >>= 1) { s += __shfl_xor(s, off); ss += __shfl_xor(ss, off); }
    int wave = d >> 6, lane = d & 63;
    if (lane == 0) { red[wave] = s; red[4 + wave] = ss; }
    __syncthreads();
    float stot = red[0] + red[1] + red[2] + red[3];
    float sstot = red[4] + red[5] + red[6] + red[7];
    float mean = stot * (1.f / DIM);
    float rstd = rsqrtf(sstot * (1.f / DIM) - mean * mean + 1e-5f);
    y[(size_t)tok * DIM + d] = f2bf((v - mean) * rstd * g[d] + bln[d]);
}

// Transpose+convert weights to bf16 [N,K]; seg 8 builds WhT [16x256] (rows 12-15 zero)
__global__ __launch_bounds__(256) void k_prep(const float* __restrict__ Wqkv,
        const float* __restrict__ Wo, const float* __restrict__ W1,
        const float* __restrict__ W2, const float* __restrict__ Wh,
        unsigned short* __restrict__ wT) {
    int seg = blockIdx.y;
    int idx = blockIdx.x * 256 + threadIdx.x;
    if (seg == 8) {
        if (idx >= 16 * 256) return;
        int u = idx >> 8, k = idx & 255;
        wT[1572864 + idx] = (u < UPD) ? f2bf(Wh[(size_t)k * UPD + u]) : (unsigned short)0;
        return;
    }
    int l = seg >> 2, mat = seg & 3;
    const float* src; int kwSh, Nw; size_t ooff;
    switch (mat) {
        case 0: src = Wqkv + (size_t)l * 196608; kwSh = 8;  Nw = 768;  ooff = (size_t)l * 786432 + 0;      break;
        case 1: src = Wo   + (size_t)l * 65536;  kwSh = 8;  Nw = 256;  ooff = (size_t)l * 786432 + 196608; break;
        case 2: src = W1   + (size_t)l * 262144; kwSh = 8;  Nw = 1024; ooff = (size_t)l * 786432 + 262144; break;
        default:src = W2   + (size_t)l * 262144; kwSh = 10; Nw = 256;  ooff = (size_t)l * 786432 + 524288; break;
    }
    int Kw = 1 << kwSh;
    if (idx >= Kw * Nw) return;
    int n = idx >> kwSh, k = idx & (Kw - 1);
    wT[ooff + idx] = f2bf(src[(size_t)k * Nw + n]);
}

// qkv GEMM, swapped-operand MFMA so each lane holds 4 consecutive n (packed 8B stores
// to head-planes [type][h][tok][32]). XCD-swizzled so all 6 n-tiles of an m-tile share an XCD.
__global__ __launch_bounds__(256) void k_qkv(const unsigned short* __restrict__ A,
        const unsigned short* __restrict__ BT, unsigned short* __restrict__ out) {
    __shared__ unsigned short As[128 * 32];
    __shared__ unsigned short Bs[128 * 32];
    const int K = 256;
    int bid = blockIdx.x;                       // 1536 blocks
    int sb = (bid & 7) * 192 + (bid >> 3);      // bijective (1536 % 8 == 0)
    int mt = sb / 6, nt = sb - mt * 6;
    int m0 = mt * 128, n0 = nt * 128;
    int t = threadIdx.x;
    int lane = t & 63, w = t >> 6;
    int wm = (w >> 1) * 64, wn = (w & 1) * 64;

    f32x4 acc[4][4] = {};
    const unsigned short* aBase = A  + (size_t)(m0 + (t >> 2)) * K + (t & 3) * 8;
    const unsigned short* bBase = BT + (size_t)(n0 + (t >> 2)) * K + (t & 3) * 8;
    unsigned short* aDst = As + t * 8;
    unsigned short* bDst = Bs + t * 8;
    int fr = lane & 15, kb = (lane >> 4) * 8;

    for (int k0 = 0; k0 < K; k0 += 32) {
        gload_lds16(aBase + k0,          aDst);
        gload_lds16(aBase + 64 * K + k0, aDst + 2048);
        gload_lds16(bBase + k0,          bDst);
        gload_lds16(bBase + 64 * K + k0, bDst + 2048);
        __syncthreads();
        bf16x8 af[4], bfv[4];
#pragma unroll
        for (int i = 0; i < 4; ++i)
            af[i] = *(const bf16x8*)&As[(wm + i * 16 + fr) * 32 + kb];
#pragma unroll
        for (int j = 0; j < 4; ++j)
            bfv[j] = *(const bf16x8*)&Bs[(wn + j * 16 + fr) * 32 + kb];
#pragma unroll
        for (int i = 0; i < 4; ++i)
#pragma unroll
            for (int j = 0; j < 4; ++j)   // swapped: D[row=n][col=m]
                acc[i][j] = __builtin_amdgcn_mfma_f32_16x16x32_bf16(bfv[j], af[i], acc[i][j], 0, 0, 0);
        __syncthreads();
    }
    int mcol = lane & 15, nq = (lane >> 4) * 4;
#pragma unroll
    for (int i = 0; i < 4; ++i) {
        int m = m0 + wm + i * 16 + mcol;
#pragma unroll
        for (int j = 0; j < 4; ++j) {
            int ng = n0 + wn + j * 16 + nq;
            int type = ng >> 8, rem = ng & 255;
            ushort4 pk;
            pk.x = f2bf(acc[i][j][0]); pk.y = f2bf(acc[i][j][1]);
            pk.z = f2bf(acc[i][j][2]); pk.w = f2bf(acc[i][j][3]);
            *(ushort4*)(out + (size_t)(type * 8 + (rem >> 5)) * HME + (size_t)m * 32 + (rem & 31)) = pk;
        }
    }
}

// Fused residual GEMM + LayerNorm, N==256. 512 threads, tile 128x256.
// ALAYOUT 1: A headwise [8][M][32] (K=256). x = A@BT + bias + x ; y = LN(x; g,b)
template<int ALAYOUT>
__global__ __launch_bounds__(512) void k_mgemm_ln(const unsigned short* __restrict__ A,
        const unsigned short* __restrict__ BT, const float* __restrict__ bias,
        const float* __restrict__ g, const float* __restrict__ bln,
        float* __restrict__ x, unsigned short* __restrict__ y, int K) {
    __shared__ unsigned short As[128 * 32];
    __shared__ unsigned short Bs[256 * 32];
    __shared__ float sred[128 * 4];
    __shared__ float ssred[128 * 4];
    __shared__ float msr[128 * 2];
    int t = threadIdx.x;
    int lane = t & 63, w = t >> 6;
    int wm = (w >> 2) * 64, wn = (w & 3) * 64, wnq = w & 3;
    int m0 = blockIdx.x * 128;

    f32x4 acc[4][4] = {};
    const unsigned short* aBase = (ALAYOUT == 0)
        ? A + (size_t)(m0 + (t >> 2)) * K + (t & 3) * 8
        : A + (size_t)(m0 + (t >> 2)) * 32 + (t & 3) * 8;
    const unsigned short* bBase = BT + (size_t)(t >> 2) * K + (t & 3) * 8;
    unsigned short* aDst = As + t * 8;
    unsigned short* bDst = Bs + t * 8;
    int fr = lane & 15, kb = (lane >> 4) * 8;

    for (int k0 = 0; k0 < K; k0 += 32) {
        const unsigned short* aSrc = (ALAYOUT == 0) ? aBase + k0 : aBase + (size_t)(k0 >> 5) * HME;
        gload_lds16(aSrc,                 aDst);
        gload_lds16(bBase + k0,           bDst);
        gload_lds16(bBase + 128 * K + k0, bDst + 4096);
        __syncthreads();
        bf16x8 af[4], bfv[4];
#pragma unroll
        for (int i = 0; i < 4; ++i)
            af[i] = *(const bf16x8*)&As[(wm + i * 16 + fr) * 32 + kb];
#pragma unroll
        for (int j = 0; j < 4; ++j)
            bfv[j] = *(const bf16x8*)&Bs[(wn + j * 16 + fr) * 32 + kb];
#pragma unroll
        for (int i = 0; i < 4; ++i)
#pragma unroll
            for (int j = 0; j < 4; ++j)
                acc[i][j] = __builtin_amdgcn_mfma_f32_16x16x32_bf16(af[i], bfv[j], acc[i][j], 0, 0, 0);
        __syncthreads();
    }

    int col = lane & 15;
    int rowq = (lane >> 4) * 4;
    float bv[4];
#pragma unroll
    for (int j = 0; j < 4; ++j) bv[j] = bias[wn + j * 16 + col];
#pragma unroll
    for (int i = 0; i < 4; ++i)
#pragma unroll
        for (int r = 0; r < 4; ++r) {
            int grow = m0 + wm + i * 16 + rowq + r;
#pragma unroll
            for (int j = 0; j < 4; ++j)
                acc[i][j][r] += bv[j] + x[(size_t)grow * DIM + wn + j * 16 + col];
        }
#pragma unroll
    for (int i = 0; i < 4; ++i)
#pragma unroll
        for (int r = 0; r < 4; ++r) {
            float s = acc[i][0][r] + acc[i][1][r] + acc[i][2][r] + acc[i][3][r];
            float ss = acc[i][0][r] * acc[i][0][r] + acc[i][1][r] * acc[i][1][r]
                     + acc[i][2][r] * acc[i][2][r] + acc[i][3][r] * acc[i][3][r];
#pragma unroll
            for (int off = 1; off < 16; off <<= 1) { s += __shfl_xor(s, off); ss += __shfl_xor(ss, off); }
            if ((lane & 15) == 0) {
                int row = wm + i * 16 + rowq + r;
                sred[row * 4 + wnq] = s;
                ssred[row * 4 + wnq] = ss;
            }
        }
    __syncthreads();
    if (t < 128) {
        float s = sred[t * 4] + sred[t * 4 + 1] + sred[t * 4 + 2] + sred[t * 4 + 3];
        float ss = ssred[t * 4] + ssred[t * 4 + 1] + ssred[t * 4 + 2] + ssred[t * 4 + 3];
        float mean = s * (1.f / DIM);
        float var = ss * (1.f / DIM) - mean * mean;
        msr[t * 2] = mean;
        msr[t * 2 + 1] = rsqrtf(var + 1e-5f);
    }
    __syncthreads();
    float gv[4], bb[4];
#pragma unroll
    for (int j = 0; j < 4; ++j) { gv[j] = g[wn + j * 16 + col]; bb[j] = bln[wn + j * 16 + col]; }
#pragma unroll
    for (int i = 0; i < 4; ++i)
#pragma unroll
        for (int r = 0; r < 4; ++r) {
            int row = wm + i * 16 + rowq + r;
            int grow = m0 + row;
            float mean = msr[row * 2], rstd = msr[row * 2 + 1];
#pragma unroll
            for (int j = 0; j < 4; ++j) {
                float v = acc[i][j][r];
                int gcol = wn + j * 16 + col;
                x[(size_t)grow * DIM + gcol] = v;
                y[(size_t)grow * DIM + gcol] = f2bf((v - mean) * rstd * gv[j] + bb[j]);
            }
        }
}

// Fused MLP v2: x += gelu(y@W1+b1)@W2 + b2 ; y = LN_next(x). 512 thr, 64-token tile.
// Hidden processed in 4 chunks of 256 cols -> Hs 32 KB, total LDS ~66 KB -> 2 blocks/CU.
__global__ __launch_bounds__(512) void k_mlp(const unsigned short* __restrict__ y_in,
        const unsigned short* __restrict__ W1T, const unsigned short* __restrict__ W2T,
        const float* __restrict__ b1, const float* __restrict__ b2,
        const float* __restrict__ g, const float* __restrict__ bln,
        float* __restrict__ x, unsigned short* __restrict__ y_out) {
    __shared__ unsigned short Ay[64 * 256];   // 32 KB, chunk-swizzled
    __shared__ unsigned short Hs[64 * 256];   // 32 KB, chunk-swizzled
    __shared__ float sred[64 * 4];
    __shared__ float ssred[64 * 4];
    __shared__ float msr[64 * 2];
    int t = threadIdx.x, lane = t & 63, w = t >> 6;
    int m0 = blockIdx.x * 64;
    int fr = lane & 15, kb8 = (lane >> 4);     // k 8-elem chunk index within 32-k step

    // stage y tile, pre-swizzled source so LDS dest stays linear (m173 pattern)
#pragma unroll
    for (int it = 0; it < 4; ++it) {
        int slot = t + it * 512;               // 0..2047, 16B chunks
        int row = slot >> 5, cp = slot & 31;
        int cl = cp ^ (row & 7);
        gload_lds16(y_in + (size_t)(m0 + row) * 256 + cl * 8, Ay + slot * 8);
    }
    asm volatile("s_waitcnt vmcnt(0)");
    __syncthreads();

    f32x4 acc2[2][4] = {};
    int m2base = (w & 1) * 32;
    int n2base = (w >> 1) * 64;

    for (int q = 0; q < 4; ++q) {
        // GEMM1: hidden chunk [64][256] = Ay @ W1T[q*256 ...], swapped operands (wave owns 32 cols)
        f32x4 acc1[4][2] = {};
        const unsigned short* w1base = W1T + (size_t)(q * 256 + w * 32) * 256;
#pragma unroll
        for (int k0 = 0; k0 < 256; k0 += 32) {
            bf16x8 af[4], bfv[2];
#pragma unroll
            for (int i = 0; i < 4; ++i) {
                int row = i * 16 + fr;
                int cp = ((k0 >> 3) + kb8) ^ (row & 7);
                af[i] = *(const bf16x8*)&Ay[row * 256 + cp * 8];
            }
#pragma unroll
            for (int j = 0; j < 2; ++j)
                bfv[j] = *(const bf16x8*)(w1base + (size_t)(j * 16 + fr) * 256 + k0 + kb8 * 8);
#pragma unroll
            for (int i = 0; i < 4; ++i)
#pragma unroll
                for (int j = 0; j < 2; ++j)
                    acc1[i][j] = __builtin_amdgcn_mfma_f32_16x16x32_bf16(bfv[j], af[i], acc1[i][j], 0, 0, 0);
        }
        __syncthreads();   // prev chunk's GEMM2 done reading Hs
        // bias1 + gelu + packed 8B writes into swizzled Hs
        int nq = (lane >> 4) * 4;
#pragma unroll
        for (int j = 0; j < 2; ++j) {
            int nl = w * 32 + j * 16 + nq;           // local col in [0,256)
            float4 b1q = *(const float4*)(b1 + q * 256 + nl);
#pragma unroll
            for (int i = 0; i < 4; ++i) {
                int m = i * 16 + (lane & 15);
                ushort4 pk;
                pk.x = f2bf(gelu_exact(acc1[i][j][0] + b1q.x));
                pk.y = f2bf(gelu_exact(acc1[i][j][1] + b1q.y));
                pk.z = f2bf(gelu_exact(acc1[i][j][2] + b1q.z));
                pk.w = f2bf(gelu_exact(acc1[i][j][3] + b1q.w));
                int cp = (nl >> 3) ^ (m & 7);
                *(ushort4*)&Hs[m * 256 + cp * 8 + (nl & 7)] = pk;
            }
        }
        __syncthreads();   // Hs visible
        // GEMM2: acc2 += Hs @ W2T[:, q*256 ...], normal operands
        const unsigned short* w2base = W2T + (size_t)n2base * 1024 + q * 256;
#pragma unroll
        for (int ks = 0; ks < 8; ++ks) {
            bf16x8 a2[2], b2f[4];
#pragma unroll
            for (int i2 = 0; i2 < 2; ++i2) {
                int row = m2base + i2 * 16 + fr;
                int cp = (ks * 4 + kb8) ^ (row & 7);
                a2[i2] = *(const bf16x8*)&Hs[row * 256 + cp * 8];
            }
#pragma unroll
            for (int j2 = 0; j2 < 4; ++j2)
                b2f[j2] = *(const bf16x8*)(w2base + (size_t)(j2 * 16 + fr) * 1024 + ks * 32 + kb8 * 8);
#pragma unroll
            for (int i2 = 0; i2 < 2; ++i2)
#pragma unroll
                for (int j2 = 0; j2 < 4; ++j2)
                    acc2[i2][j2] = __builtin_amdgcn_mfma_f32_16x16x32_bf16(a2[i2], b2f[j2], acc2[i2][j2], 0, 0, 0);
        }
        __syncthreads();   // done reading Hs before next chunk overwrites (merged w/ top barrier next iter)
    }
    // epilogue: + b2 + resid x -> LN -> write x (f32) and y_out (bf16)
    int col = lane & 15, rowq = (lane >> 4) * 4;
    float b2v[4];
#pragma unroll
    for (int j2 = 0; j2 < 4; ++j2) b2v[j2] = b2[n2base + j2 * 16 + col];
#pragma unroll
    for (int i2 = 0; i2 < 2; ++i2)
#pragma unroll
        for (int r = 0; r < 4; ++r) {
            int ml = m2base + i2 * 16 + rowq + r;
            int grow = m0 + ml;
#pragma unroll
            for (int j2 = 0; j2 < 4; ++j2)
                acc2[i2][j2][r] += b2v[j2] + x[(size_t)grow * DIM + n2base + j2 * 16 + col];
            float s = acc2[i2][0][r] + acc2[i2][1][r] + acc2[i2][2][r] + acc2[i2][3][r];
            float ss = acc2[i2][0][r] * acc2[i2][0][r] + acc2[i2][1][r] * acc2[i2][1][r]
                     + acc2[i2][2][r] * acc2[i2][2][r] + acc2[i2][3][r] * acc2[i2][3][r];
#pragma unroll
            for (int off = 1; off < 16; off <<= 1) { s += __shfl_xor(s, off); ss += __shfl_xor(ss, off); }
            if ((lane & 15) == 0) {
                sred[ml * 4 + (w >> 1)] = s;
                ssred[ml * 4 + (w >> 1)] = ss;
            }
        }
    __syncthreads();
    if (t < 64) {
        float s = sred[t * 4] + sred[t * 4 + 1] + sred[t * 4 + 2] + sred[t * 4 + 3];
        float ss = ssred[t * 4] + ssred[t * 4 + 1] + ssred[t * 4 + 2] + ssred[t * 4 + 3];
        float mean = s * (1.f / DIM);
        float var = ss * (1.f / DIM) - mean * mean;
        msr[t * 2] = mean;
        msr[t * 2 + 1] = rsqrtf(var + 1e-5f);
    }
    __syncthreads();
    float gv[4], bb[4];
#pragma unroll
    for (int j2 = 0; j2 < 4; ++j2) {
        gv[j2] = g[n2base + j2 * 16 + col];
        bb[j2] = bln[n2base + j2 * 16 + col];
    }
#pragma unroll
    for (int i2 = 0; i2 < 2; ++i2)
#pragma unroll
        for (int r = 0; r < 4; ++r) {
            int ml = m2base + i2 * 16 + rowq + r;
            int grow = m0 + ml;
            float mean = msr[ml * 2], rstd = msr[ml * 2 + 1];
#pragma unroll
            for (int j2 = 0; j2 < 4; ++j2) {
                float v = acc2[i2][j2][r];
                int gcol = n2base + j2 * 16 + col;
                x[(size_t)grow * DIM + gcol] = v;
                y_out[(size_t)grow * DIM + gcol] = f2bf((v - mean) * rstd * gv[j2] + bb[j2]);
            }
        }
}

// thread-per-(token,head) local 3x3 attention, headwise layout, no cross-lane ops.
__global__ __launch_bounds__(256) void k_attn(const unsigned short* __restrict__ qkvH,
        unsigned short* __restrict__ attnH) {
    int t = threadIdx.x;
    int h = t >> 5, tl = t & 31;
    int tok = blockIdx.x * 32 + tl;
    int b = tok >> 12, n = tok & 4095;
    int r = n >> 6, c = n & 63;

    float q[32];
    {
        const uint4* u = (const uint4*)(qkvH + (size_t)h * HME + (size_t)tok * 32);
#pragma unroll
        for (int i = 0; i < 4; ++i) {
            uint4 x4 = u[i];
            unsigned wv[4] = {x4.x, x4.y, x4.z, x4.w};
#pragma unroll
            for (int wj = 0; wj < 4; ++wj) {
                q[i * 8 + wj * 2]     = __uint_as_float(wv[wj] << 16);
                q[i * 8 + wj * 2 + 1] = __uint_as_float(wv[wj] & 0xffff0000u);
            }
        }
    }
    int nts[9];
    float dots[9];
    const unsigned short* kbase = qkvH + (size_t)(8 + h) * HME;
#pragma unroll
    for (int ki = 0; ki < 3; ++ki)
#pragma unroll
        for (int kj = 0; kj < 3; ++kj) {
            int rr = (r + ki - 1) & 63, cc = (c + kj - 1) & 63;
            int nt = (b << 12) + (rr << 6) + cc;
            nts[ki * 3 + kj] = nt;
            const uint4* u = (const uint4*)(kbase + (size_t)nt * 32);
            float acc = 0.f;
#pragma unroll
            for (int i = 0; i < 4; ++i) {
                uint4 x4 = u[i];
                unsigned wv[4] = {x4.x, x4.y, x4.z, x4.w};
#pragma unroll
                for (int wj = 0; wj < 4; ++wj) {
                    acc += __uint_as_float(wv[wj] << 16)        * q[i * 8 + wj * 2];
                    acc += __uint_as_float(wv[wj] & 0xffff0000u) * q[i * 8 + wj * 2 + 1];
                }
            }
            dots[ki * 3 + kj] = acc * 0.17677669529f;
        }
    float m = dots[0];
#pragma unroll
    for (int j = 1; j < 9; ++j) m = fmaxf(m, dots[j]);
    float sum = 0.f;
#pragma unroll
    for (int j = 0; j < 9; ++j) { dots[j] = __expf(dots[j] - m); sum += dots[j]; }
    float inv = 1.f / sum;
    float o[32] = {};
    const unsigned short* vbase = qkvH + (size_t)(16 + h) * HME;
#pragma unroll
    for (int j = 0; j < 9; ++j) {
        float wgt = dots[j] * inv;
        const uint4* u = (const uint4*)(vbase + (size_t)nts[j] * 32);
#pragma unroll
        for (int i = 0; i < 4; ++i) {
            uint4 x4 = u[i];
            unsigned wv[4] = {x4.x, x4.y, x4.z, x4.w};
#pragma unroll
            for (int wj = 0; wj < 4; ++wj) {
                o[i * 8 + wj * 2]     += wgt * __uint_as_float(wv[wj] << 16);
                o[i * 8 + wj * 2 + 1] += wgt * __uint_as_float(wv[wj] & 0xffff0000u);
            }
        }
    }
    uint4 st[4];
    unsigned* sw = (unsigned*)st;
#pragma unroll
    for (int i = 0; i < 16; ++i)
        sw[i] = (unsigned)f2bf(o[2 * i]) | ((unsigned)f2bf(o[2 * i + 1]) << 16);
    uint4* od = (uint4*)(attnH + (size_t)h * HME + (size_t)tok * 32);
#pragma unroll
    for (int i = 0; i < 4; ++i) od[i] = st[i];
}

// head GEMV via MFMA: Cg[32768,16] = y[32768,256] @ WhT[16,256]^T
__global__ __launch_bounds__(256) void k_headgemv(const unsigned short* __restrict__ y,
        const unsigned short* __restrict__ WhT, float* __restrict__ Cg) {
    int t = threadIdx.x, lane = t & 63, w = t >> 6;
    int m0 = blockIdx.x * 64 + w * 16;
    int fr = lane & 15, kb = (lane >> 4) * 8;
    f32x4 acc = {};
    const unsigned short* aRow = y + (size_t)(m0 + fr) * DIM + kb;
    const unsigned short* bRow = WhT + (size_t)fr * DIM + kb;
#pragma unroll
    for (int k0 = 0; k0 < DIM; k0 += 32) {
        bf16x8 a = *(const bf16x8*)(aRow + k0);
        bf16x8 bfr = *(const bf16x8*)(bRow + k0);
        acc = __builtin_amdgcn_mfma_f32_16x16x32_bf16(a, bfr, acc, 0, 0, 0);
    }
    int col = lane & 15, rowq = (lane >> 4) * 4;
#pragma unroll
    for (int r = 0; r < 4; ++r)
        Cg[(size_t)(m0 + rowq + r) * 16 + col] = acc[r];
}

// out[b,c,n] = cells[b,c,n] + (c>=3 ? Cg[tok,c-3] + bh[c-3] : 0)
__global__ __launch_bounds__(256) void k_assemble(const float* __restrict__ cells,
        const float* __restrict__ Cg, const float* __restrict__ bh,
        float* __restrict__ outp) {
    int idx = blockIdx.x * 256 + threadIdx.x;
    int total = BATCH * CELL_DIM * (NTOK / 4);
    if (idx >= total) return;
    int n4 = idx & 1023;
    int c = (idx >> 10) % CELL_DIM;
    int b = idx / (CELL_DIM * 1024);
    size_t ci = ((size_t)b * CELL_DIM + c) * NTOK + n4 * 4;
    float4 o = *(const float4*)(cells + ci);
    if (c >= PE_IN) {
        int u = c - PE_IN;
        float bias = bh[u];
        size_t tok = (size_t)b * NTOK + n4 * 4;
        o.x += Cg[(tok + 0) * 16 + u] + bias;
        o.y += Cg[(tok + 1) * 16 + u] + bias;
        o.z += Cg[(tok + 2) * 16 + u] + bias;
        o.w += Cg[(tok + 3) * 16 + u] + bias;
    }
    *(float4*)(outp + ci) = o;
}

extern "C" void kernel_launch(void* const* d_in, const int* in_sizes, int n_in,
                              void* d_out, int out_size, void* d_ws, size_t ws_size,
                              hipStream_t stream) {
    const float* cells = (const float*)d_in[0];
    const float* We    = (const float*)d_in[1];
    const float* be    = (const float*)d_in[2];
    const float* ln1_g = (const float*)d_in[3];
    const float* ln1_b = (const float*)d_in[4];
    const float* Wqkv  = (const float*)d_in[5];
    const float* Wo    = (const float*)d_in[6];
    const float* bo    = (const float*)d_in[7];
    const float* ln2_g = (const float*)d_in[8];
    const float* ln2_b = (const float*)d_in[9];
    const float* W1    = (const float*)d_in[10];
    const float* b1    = (const float*)d_in[11];
    const float* W2    = (const float*)d_in[12];
    const float* b2    = (const float*)d_in[13];
    const float* lnh_g = (const float*)d_in[14];
    const float* lnh_b = (const float*)d_in[15];
    const float* Wh    = (const float*)d_in[16];
    const float* bh    = (const float*)d_in[17];
    float* outp = (float*)d_out;

    char* ws = (char*)d_ws;
    float* x = (float*)ws;                                        // 33.5 MB f32 residual
    unsigned short* y = (unsigned short*)(ws + 33554432);         // 16.8 MB bf16 LN-out
    unsigned short* scratch = (unsigned short*)(ws + 50331648);   // 67 MB: qkvH+attnH / Cg
    unsigned short* wT = (unsigned short*)(ws + 117440512);       // 3 MB + 8KB transposed weights
    unsigned short* qkvH  = scratch;                              // [3][8][M][32] = 50.3 MB
    unsigned short* attnH = scratch + 24 * HME;                   // [8][M][32]   = 16.8 MB
    float* Cg = (float*)scratch;                                  // reuse after last mlp

    k_prep<<<dim3(1024, 9), 256, 0, stream>>>(Wqkv, Wo, W1, W2, Wh, wT);
    k_embed<<<M_TOK, 256, 0, stream>>>(cells, We, be, ln1_g, ln1_b, x, y);
    for (int l = 0; l < 2; ++l) {
        const unsigned short* wL = wT + (size_t)l * 786432;
        const float* gN = (l == 0) ? ln1_g + DIM : lnh_g;
        const float* bN = (l == 0) ? ln1_b + DIM : lnh_b;
        k_qkv<<<1536, 256, 0, stream>>>(y, wL + 0, qkvH);
        k_attn<<<M_TOK / 32, 256, 0, stream>>>(qkvH, attnH);
        k_mgemm_ln<1><<<M_TOK / 128, 512, 0, stream>>>(
            attnH, wL + 196608, bo + l * DIM, ln2_g + l * DIM, ln2_b + l * DIM, x, y, DIM);
        k_mlp<<<M_TOK / 64, 512, 0, stream>>>(
            y, wL + 262144, wL + 524288, b1 + l * MLP_DIM, b2 + l * DIM, gN, bN, x, y);
    }
    k_headgemv<<<M_TOK / 64, 256, 0, stream>>>(y, wT + 1572864, Cg);
    k_assemble<<<(BATCH * CELL_DIM * (NTOK / 4) + 255) / 256, 256, 0, stream>>>(cells, Cg, bh, outp);
}

// Round 7
// 385.789 us; speedup vs baseline: 1.2055x; 1.2055x over previous
//
#include <hip/hip_runtime.h>
#include <hip/hip_bf16.h>
#include <math.h>

#define HEADS 8
#define HEAD_DIM 32
#define DIM 256
#define MLP_DIM 1024
#define NTOK 4096
#define BATCH 8
#define M_TOK (BATCH*NTOK)
#define CELL_DIM 15
#define PE_IN 3
#define UPD 12
#define HME ((size_t)M_TOK*32)   // elements per head-plane [tok][32]

typedef __attribute__((ext_vector_type(8))) short bf16x8;
typedef __attribute__((ext_vector_type(4))) float f32x4;

static __device__ __forceinline__ float bf2f(unsigned short u) {
    return __uint_as_float(((unsigned int)u) << 16);
}
static __device__ __forceinline__ unsigned short f2bf(float f) {
    __hip_bfloat16 h = __float2bfloat16(f);
    union { __hip_bfloat16 h; unsigned short u; } cv; cv.h = h; return cv.u;
}
static __device__ __forceinline__ void gload_lds16(const unsigned short* g, unsigned short* l) {
    __builtin_amdgcn_global_load_lds(
        (const __attribute__((address_space(1))) void*)g,
        (__attribute__((address_space(3))) void*)l, 16, 0, 0);
}
static __device__ __forceinline__ float gelu_exact(float v) {
    return v * 0.5f * (1.f + erff(v * 0.70710678118f));
}

// embed + fused LN1[0]: x = cells@We + be + pe ; y = LN(x)
__global__ __launch_bounds__(256) void k_embed(const float* __restrict__ cells,
        const float* __restrict__ We, const float* __restrict__ be,
        const float* __restrict__ g, const float* __restrict__ bln,
        float* __restrict__ x, unsigned short* __restrict__ y) {
    __shared__ float red[8];
    int tok = blockIdx.x;
    int d = threadIdx.x;
    int b = tok >> 12, n = tok & 4095;
    const float* cb = cells + (size_t)b * CELL_DIM * NTOK + n;
    float acc = 0.f;
#pragma unroll
    for (int c = 0; c < CELL_DIM; ++c)
        acc += cb[c * NTOK] * We[c * DIM + d];
    int i = d >> 1;
    float freq = expf(-logf(10000.f) * (float)(2 * i) / (float)DIM);
    float ph = (float)n * freq;
    float pe = (d & 1) ? cosf(ph) : sinf(ph);
    float v = acc + be[d] + pe;
    x[(size_t)tok * DIM + d] = v;
    float s = v, ss = v * v;
#pragma unroll
    for (int off = 32; off; off >>= 1) { s += __shfl_xor(s, off); ss += __shfl_xor(ss, off); }
    int wave = d >> 6, lane = d & 63;
    if (lane == 0) { red[wave] = s; red[4 + wave] = ss; }
    __syncthreads();
    float stot = red[0] + red[1] + red[2] + red[3];
    float sstot = red[4] + red[5] + red[6] + red[7];
    float mean = stot * (1.f / DIM);
    float rstd = rsqrtf(sstot * (1.f / DIM) - mean * mean + 1e-5f);
    y[(size_t)tok * DIM + d] = f2bf((v - mean) * rstd * g[d] + bln[d]);
}

// Transpose+convert weights to bf16 [N,K]; seg 8 builds WhT [16x256] (rows 12-15 zero)
__global__ __launch_bounds__(256) void k_prep(const float* __restrict__ Wqkv,
        const float* __restrict__ Wo, const float* __restrict__ W1,
        const float* __restrict__ W2, const float* __restrict__ Wh,
        unsigned short* __restrict__ wT) {
    int seg = blockIdx.y;
    int idx = blockIdx.x * 256 + threadIdx.x;
    if (seg == 8) {
        if (idx >= 16 * 256) return;
        int u = idx >> 8, k = idx & 255;
        wT[1572864 + idx] = (u < UPD) ? f2bf(Wh[(size_t)k * UPD + u]) : (unsigned short)0;
        return;
    }
    int l = seg >> 2, mat = seg & 3;
    const float* src; int kwSh, Nw; size_t ooff;
    switch (mat) {
        case 0: src = Wqkv + (size_t)l * 196608; kwSh = 8;  Nw = 768;  ooff = (size_t)l * 786432 + 0;      break;
        case 1: src = Wo   + (size_t)l * 65536;  kwSh = 8;  Nw = 256;  ooff = (size_t)l * 786432 + 196608; break;
        case 2: src = W1   + (size_t)l * 262144; kwSh = 8;  Nw = 1024; ooff = (size_t)l * 786432 + 262144; break;
        default:src = W2   + (size_t)l * 262144; kwSh = 10; Nw = 256;  ooff = (size_t)l * 786432 + 524288; break;
    }
    int Kw = 1 << kwSh;
    if (idx >= Kw * Nw) return;
    int n = idx >> kwSh, k = idx & (Kw - 1);
    wT[ooff + idx] = f2bf(src[(size_t)k * Nw + n]);
}

// Double-buffered MFMA GEMM: C[M,N] = A[M,K](bf16) @ BT[N,K]^T.
// EPI1: gelu(+bias) -> bf16 row-major [M,N]
// EPI3: swapped-operand MFMA, packed 8B stores to head-planes [type][h][tok][32]
// 1D grid with bijective XCD swizzle; NT = number of n-tiles.
template<int EPI>
__global__ __launch_bounds__(256) void k_mgemm(const unsigned short* __restrict__ A,
        const unsigned short* __restrict__ BT, const float* __restrict__ bias,
        void* __restrict__ Cout, int M, int N, int K, int NT) {
    __shared__ unsigned short As[2][128 * 32];
    __shared__ unsigned short Bs[2][128 * 32];
    int bid = blockIdx.x;
    int cpx = gridDim.x >> 3;                   // gridDim.x % 8 == 0
    int sb = (bid & 7) * cpx + (bid >> 3);
    int mt = sb / NT, nt = sb - mt * NT;
    int m0 = mt * 128, n0 = nt * 128;
    int t = threadIdx.x;
    int lane = t & 63, w = t >> 6;
    int wm = (w >> 1) * 64, wn = (w & 1) * 64;
    f32x4 acc[4][4] = {};
    const unsigned short* aBase = A  + (size_t)(m0 + (t >> 2)) * K + (t & 3) * 8;
    const unsigned short* bBase = BT + (size_t)(n0 + (t >> 2)) * K + (t & 3) * 8;
    int fr = lane & 15, kb = (lane >> 4) * 8;

    auto stage = [&](int buf, int k0) {
        gload_lds16(aBase + k0,          &As[buf][t * 8]);
        gload_lds16(aBase + 64 * K + k0, &As[buf][2048 + t * 8]);
        gload_lds16(bBase + k0,          &Bs[buf][t * 8]);
        gload_lds16(bBase + 64 * K + k0, &Bs[buf][2048 + t * 8]);
    };
    auto compute = [&](int buf) {
        bf16x8 af[4], bfv[4];
#pragma unroll
        for (int i = 0; i < 4; ++i)
            af[i] = *(const bf16x8*)&As[buf][(wm + i * 16 + fr) * 32 + kb];
#pragma unroll
        for (int j = 0; j < 4; ++j)
            bfv[j] = *(const bf16x8*)&Bs[buf][(wn + j * 16 + fr) * 32 + kb];
#pragma unroll
        for (int i = 0; i < 4; ++i)
#pragma unroll
            for (int j = 0; j < 4; ++j)
                acc[i][j] = (EPI == 3)
                    ? __builtin_amdgcn_mfma_f32_16x16x32_bf16(bfv[j], af[i], acc[i][j], 0, 0, 0)
                    : __builtin_amdgcn_mfma_f32_16x16x32_bf16(af[i], bfv[j], acc[i][j], 0, 0, 0);
    };

    stage(0, 0);
    __syncthreads();
    int cur = 0;
    for (int k0 = 32; k0 < K; k0 += 32) {
        stage(cur ^ 1, k0);       // issue next tile's loads first
        compute(cur);             // MFMA on current tile hides the load latency
        __syncthreads();          // implicit vmcnt(0): next tile landed
        cur ^= 1;
    }
    compute(cur);

    if (EPI == 3) {
        int mcol = lane & 15, nq = (lane >> 4) * 4;
#pragma unroll
        for (int i = 0; i < 4; ++i) {
            int m = m0 + wm + i * 16 + mcol;
#pragma unroll
            for (int j = 0; j < 4; ++j) {
                int ng = n0 + wn + j * 16 + nq;
                int type = ng >> 8, rem = ng & 255;
                ushort4 pk;
                pk.x = f2bf(acc[i][j][0]); pk.y = f2bf(acc[i][j][1]);
                pk.z = f2bf(acc[i][j][2]); pk.w = f2bf(acc[i][j][3]);
                *(ushort4*)((unsigned short*)Cout +
                    (size_t)(type * 8 + (rem >> 5)) * HME + (size_t)m * 32 + (rem & 31)) = pk;
            }
        }
    } else {
        int col = lane & 15;
        int rowq = (lane >> 4) * 4;
#pragma unroll
        for (int j = 0; j < 4; ++j) {
            int gcol = n0 + wn + j * 16 + col;
            float bv = bias ? bias[gcol] : 0.f;
#pragma unroll
            for (int i = 0; i < 4; ++i)
#pragma unroll
                for (int r = 0; r < 4; ++r) {
                    int grow = m0 + wm + i * 16 + rowq + r;
                    float v = acc[i][j][r] + bv;
                    if (EPI == 1) v = gelu_exact(v);
                    ((unsigned short*)Cout)[(size_t)grow * N + gcol] = f2bf(v);
                }
        }
    }
}

// Double-buffered fused residual GEMM + LayerNorm, N==256. 512 threads, tile 128x256.
// ALAYOUT 0: A[M,K] row-major ; ALAYOUT 1: A headwise [8][M][32] (K=256)
// x = A@BT + bias + x ; y = LN(x; g,b)
template<int ALAYOUT>
__global__ __launch_bounds__(512) void k_mgemm_ln(const unsigned short* __restrict__ A,
        const unsigned short* __restrict__ BT, const float* __restrict__ bias,
        const float* __restrict__ g, const float* __restrict__ bln,
        float* __restrict__ x, unsigned short* __restrict__ y, int K) {
    __shared__ unsigned short As[2][128 * 32];
    __shared__ unsigned short Bs[2][256 * 32];
    __shared__ float sred[128 * 4];
    __shared__ float ssred[128 * 4];
    __shared__ float msr[128 * 2];
    int t = threadIdx.x;
    int lane = t & 63, w = t >> 6;
    int wm = (w >> 2) * 64, wn = (w & 3) * 64, wnq = w & 3;
    int m0 = blockIdx.x * 128;

    f32x4 acc[4][4] = {};
    const unsigned short* aBase = (ALAYOUT == 0)
        ? A + (size_t)(m0 + (t >> 2)) * K + (t & 3) * 8
        : A + (size_t)(m0 + (t >> 2)) * 32 + (t & 3) * 8;
    const unsigned short* bBase = BT + (size_t)(t >> 2) * K + (t & 3) * 8;
    int fr = lane & 15, kb = (lane >> 4) * 8;

    auto stage = [&](int buf, int k0) {
        const unsigned short* aSrc = (ALAYOUT == 0) ? aBase + k0 : aBase + (size_t)(k0 >> 5) * HME;
        gload_lds16(aSrc,                 &As[buf][t * 8]);
        gload_lds16(bBase + k0,           &Bs[buf][t * 8]);
        gload_lds16(bBase + 128 * K + k0, &Bs[buf][4096 + t * 8]);
    };
    auto compute = [&](int buf) {
        bf16x8 af[4], bfv[4];
#pragma unroll
        for (int i = 0; i < 4; ++i)
            af[i] = *(const bf16x8*)&As[buf][(wm + i * 16 + fr) * 32 + kb];
#pragma unroll
        for (int j = 0; j < 4; ++j)
            bfv[j] = *(const bf16x8*)&Bs[buf][(wn + j * 16 + fr) * 32 + kb];
#pragma unroll
        for (int i = 0; i < 4; ++i)
#pragma unroll
            for (int j = 0; j < 4; ++j)
                acc[i][j] = __builtin_amdgcn_mfma_f32_16x16x32_bf16(af[i], bfv[j], acc[i][j], 0, 0, 0);
    };

    stage(0, 0);
    __syncthreads();
    int cur = 0;
    for (int k0 = 32; k0 < K; k0 += 32) {
        stage(cur ^ 1, k0);
        compute(cur);
        __syncthreads();
        cur ^= 1;
    }
    compute(cur);

    int col = lane & 15;
    int rowq = (lane >> 4) * 4;
    float bv[4];
#pragma unroll
    for (int j = 0; j < 4; ++j) bv[j] = bias[wn + j * 16 + col];
#pragma unroll
    for (int i = 0; i < 4; ++i)
#pragma unroll
        for (int r = 0; r < 4; ++r) {
            int grow = m0 + wm + i * 16 + rowq + r;
#pragma unroll
            for (int j = 0; j < 4; ++j)
                acc[i][j][r] += bv[j] + x[(size_t)grow * DIM + wn + j * 16 + col];
        }
#pragma unroll
    for (int i = 0; i < 4; ++i)
#pragma unroll
        for (int r = 0; r < 4; ++r) {
            float s = acc[i][0][r] + acc[i][1][r] + acc[i][2][r] + acc[i][3][r];
            float ss = acc[i][0][r] * acc[i][0][r] + acc[i][1][r] * acc[i][1][r]
                     + acc[i][2][r] * acc[i][2][r] + acc[i][3][r] * acc[i][3][r];
#pragma unroll
            for (int off = 1; off < 16; off <<= 1) { s += __shfl_xor(s, off); ss += __shfl_xor(ss, off); }
            if ((lane & 15) == 0) {
                int row = wm + i * 16 + rowq + r;
                sred[row * 4 + wnq] = s;
                ssred[row * 4 + wnq] = ss;
            }
        }
    __syncthreads();
    if (t < 128) {
        float s = sred[t * 4] + sred[t * 4 + 1] + sred[t * 4 + 2] + sred[t * 4 + 3];
        float ss = ssred[t * 4] + ssred[t * 4 + 1] + ssred[t * 4 + 2] + ssred[t * 4 + 3];
        float mean = s * (1.f / DIM);
        float var = ss * (1.f / DIM) - mean * mean;
        msr[t * 2] = mean;
        msr[t * 2 + 1] = rsqrtf(var + 1e-5f);
    }
    __syncthreads();
    float gv[4], bb[4];
#pragma unroll
    for (int j = 0; j < 4; ++j) { gv[j] = g[wn + j * 16 + col]; bb[j] = bln[wn + j * 16 + col]; }
#pragma unroll
    for (int i = 0; i < 4; ++i)
#pragma unroll
        for (int r = 0; r < 4; ++r) {
            int row = wm + i * 16 + rowq + r;
            int grow = m0 + row;
            float mean = msr[row * 2], rstd = msr[row * 2 + 1];
#pragma unroll
            for (int j = 0; j < 4; ++j) {
                float v = acc[i][j][r];
                int gcol = wn + j * 16 + col;
                x[(size_t)grow * DIM + gcol] = v;
                y[(size_t)grow * DIM + gcol] = f2bf((v - mean) * rstd * gv[j] + bb[j]);
            }
        }
}

// thread-per-(token,head) local 3x3 attention, headwise layout, no cross-lane ops.
__global__ __launch_bounds__(256) void k_attn(const unsigned short* __restrict__ qkvH,
        unsigned short* __restrict__ attnH) {
    int t = threadIdx.x;
    int h = t >> 5, tl = t & 31;
    int tok = blockIdx.x * 32 + tl;
    int b = tok >> 12, n = tok & 4095;
    int r = n >> 6, c = n & 63;

    float q[32];
    {
        const uint4* u = (const uint4*)(qkvH + (size_t)h * HME + (size_t)tok * 32);
#pragma unroll
        for (int i = 0; i < 4; ++i) {
            uint4 x4 = u[i];
            unsigned wv[4] = {x4.x, x4.y, x4.z, x4.w};
#pragma unroll
            for (int wj = 0; wj < 4; ++wj) {
                q[i * 8 + wj * 2]     = __uint_as_float(wv[wj] << 16);
                q[i * 8 + wj * 2 + 1] = __uint_as_float(wv[wj] & 0xffff0000u);
            }
        }
    }
    int nts[9];
    float dots[9];
    const unsigned short* kbase = qkvH + (size_t)(8 + h) * HME;
#pragma unroll
    for (int ki = 0; ki < 3; ++ki)
#pragma unroll
        for (int kj = 0; kj < 3; ++kj) {
            int rr = (r + ki - 1) & 63, cc = (c + kj - 1) & 63;
            int nt = (b << 12) + (rr << 6) + cc;
            nts[ki * 3 + kj] = nt;
            const uint4* u = (const uint4*)(kbase + (size_t)nt * 32);
            float acc = 0.f;
#pragma unroll
            for (int i = 0; i < 4; ++i) {
                uint4 x4 = u[i];
                unsigned wv[4] = {x4.x, x4.y, x4.z, x4.w};
#pragma unroll
                for (int wj = 0; wj < 4; ++wj) {
                    acc += __uint_as_float(wv[wj] << 16)        * q[i * 8 + wj * 2];
                    acc += __uint_as_float(wv[wj] & 0xffff0000u) * q[i * 8 + wj * 2 + 1];
                }
            }
            dots[ki * 3 + kj] = acc * 0.17677669529f;
        }
    float m = dots[0];
#pragma unroll
    for (int j = 1; j < 9; ++j) m = fmaxf(m, dots[j]);
    float sum = 0.f;
#pragma unroll
    for (int j = 0; j < 9; ++j) { dots[j] = __expf(dots[j] - m); sum += dots[j]; }
    float inv = 1.f / sum;
    float o[32] = {};
    const unsigned short* vbase = qkvH + (size_t)(16 + h) * HME;
#pragma unroll
    for (int j = 0; j < 9; ++j) {
        float wgt = dots[j] * inv;
        const uint4* u = (const uint4*)(vbase + (size_t)nts[j] * 32);
#pragma unroll
        for (int i = 0; i < 4; ++i) {
            uint4 x4 = u[i];
            unsigned wv[4] = {x4.x, x4.y, x4.z, x4.w};
#pragma unroll
            for (int wj = 0; wj < 4; ++wj) {
                o[i * 8 + wj * 2]     += wgt * __uint_as_float(wv[wj] << 16);
                o[i * 8 + wj * 2 + 1] += wgt * __uint_as_float(wv[wj] & 0xffff0000u);
            }
        }
    }
    uint4 st[4];
    unsigned* sw = (unsigned*)st;
#pragma unroll
    for (int i = 0; i < 16; ++i)
        sw[i] = (unsigned)f2bf(o[2 * i]) | ((unsigned)f2bf(o[2 * i + 1]) << 16);
    uint4* od = (uint4*)(attnH + (size_t)h * HME + (size_t)tok * 32);
#pragma unroll
    for (int i = 0; i < 4; ++i) od[i] = st[i];
}

// head GEMV via MFMA: Cg[32768,16] = y[32768,256] @ WhT[16,256]^T
__global__ __launch_bounds__(256) void k_headgemv(const unsigned short* __restrict__ y,
        const unsigned short* __restrict__ WhT, float* __restrict__ Cg) {
    int t = threadIdx.x, lane = t & 63, w = t >> 6;
    int m0 = blockIdx.x * 64 + w * 16;
    int fr = lane & 15, kb = (lane >> 4) * 8;
    f32x4 acc = {};
    const unsigned short* aRow = y + (size_t)(m0 + fr) * DIM + kb;
    const unsigned short* bRow = WhT + (size_t)fr * DIM + kb;
#pragma unroll
    for (int k0 = 0; k0 < DIM; k0 += 32) {
        bf16x8 a = *(const bf16x8*)(aRow + k0);
        bf16x8 bfr = *(const bf16x8*)(bRow + k0);
        acc = __builtin_amdgcn_mfma_f32_16x16x32_bf16(a, bfr, acc, 0, 0, 0);
    }
    int col = lane & 15, rowq = (lane >> 4) * 4;
#pragma unroll
    for (int r = 0; r < 4; ++r)
        Cg[(size_t)(m0 + rowq + r) * 16 + col] = acc[r];
}

// out[b,c,n] = cells[b,c,n] + (c>=3 ? Cg[tok,c-3] + bh[c-3] : 0)
__global__ __launch_bounds__(256) void k_assemble(const float* __restrict__ cells,
        const float* __restrict__ Cg, const float* __restrict__ bh,
        float* __restrict__ outp) {
    int idx = blockIdx.x * 256 + threadIdx.x;
    int total = BATCH * CELL_DIM * (NTOK / 4);
    if (idx >= total) return;
    int n4 = idx & 1023;
    int c = (idx >> 10) % CELL_DIM;
    int b = idx / (CELL_DIM * 1024);
    size_t ci = ((size_t)b * CELL_DIM + c) * NTOK + n4 * 4;
    float4 o = *(const float4*)(cells + ci);
    if (c >= PE_IN) {
        int u = c - PE_IN;
        float bias = bh[u];
        size_t tok = (size_t)b * NTOK + n4 * 4;
        o.x += Cg[(tok + 0) * 16 + u] + bias;
        o.y += Cg[(tok + 1) * 16 + u] + bias;
        o.z += Cg[(tok + 2) * 16 + u] + bias;
        o.w += Cg[(tok + 3) * 16 + u] + bias;
    }
    *(float4*)(outp + ci) = o;
}

extern "C" void kernel_launch(void* const* d_in, const int* in_sizes, int n_in,
                              void* d_out, int out_size, void* d_ws, size_t ws_size,
                              hipStream_t stream) {
    const float* cells = (const float*)d_in[0];
    const float* We    = (const float*)d_in[1];
    const float* be    = (const float*)d_in[2];
    const float* ln1_g = (const float*)d_in[3];
    const float* ln1_b = (const float*)d_in[4];
    const float* Wqkv  = (const float*)d_in[5];
    const float* Wo    = (const float*)d_in[6];
    const float* bo    = (const float*)d_in[7];
    const float* ln2_g = (const float*)d_in[8];
    const float* ln2_b = (const float*)d_in[9];
    const float* W1    = (const float*)d_in[10];
    const float* b1    = (const float*)d_in[11];
    const float* W2    = (const float*)d_in[12];
    const float* b2    = (const float*)d_in[13];
    const float* lnh_g = (const float*)d_in[14];
    const float* lnh_b = (const float*)d_in[15];
    const float* Wh    = (const float*)d_in[16];
    const float* bh    = (const float*)d_in[17];
    float* outp = (float*)d_out;

    char* ws = (char*)d_ws;
    float* x = (float*)ws;                                        // 33.5 MB f32 residual
    unsigned short* y = (unsigned short*)(ws + 33554432);         // 16.8 MB bf16 LN-out
    unsigned short* scratch = (unsigned short*)(ws + 50331648);   // 67.1 MB: qkvH+attnH / hidden / Cg
    unsigned short* wT = (unsigned short*)(ws + 117440512);       // 3 MB + 8KB transposed weights
    unsigned short* qkvH  = scratch;                              // [3][8][M][32] = 50.3 MB
    unsigned short* attnH = scratch + 24 * HME;                   // [8][M][32]   = 16.8 MB
    unsigned short* hidden = scratch;                             // [M][1024] = 67.1 MB (qkv dead by mlp1)
    float* Cg = (float*)scratch;                                  // reuse after last mlp2

    k_prep<<<dim3(1024, 9), 256, 0, stream>>>(Wqkv, Wo, W1, W2, Wh, wT);
    k_embed<<<M_TOK, 256, 0, stream>>>(cells, We, be, ln1_g, ln1_b, x, y);
    for (int l = 0; l < 2; ++l) {
        const unsigned short* wL = wT + (size_t)l * 786432;
        const float* gN = (l == 0) ? ln1_g + DIM : lnh_g;
        const float* bN = (l == 0) ? ln1_b + DIM : lnh_b;
        k_qkvStep: ;
        k_mgemm<3><<<1536, 256, 0, stream>>>(
            y, wL + 0, nullptr, qkvH, M_TOK, 768, DIM, 6);
        k_attn<<<M_TOK / 32, 256, 0, stream>>>(qkvH, attnH);
        k_mgemm_ln<1><<<M_TOK / 128, 512, 0, stream>>>(
            attnH, wL + 196608, bo + l * DIM, ln2_g + l * DIM, ln2_b + l * DIM, x, y, DIM);
        k_mgemm<1><<<2048, 256, 0, stream>>>(
            y, wL + 262144, b1 + l * MLP_DIM, hidden, M_TOK, MLP_DIM, DIM, 8);
        k_mgemm_ln<0><<<M_TOK / 128, 512, 0, stream>>>(
            hidden, wL + 524288, b2 + l * DIM, gN, bN, x, y, MLP_DIM);
    }
    k_headgemv<<<M_TOK / 64, 256, 0, stream>>>(y, wT + 1572864, Cg);
    k_assemble<<<(BATCH * CELL_DIM * (NTOK / 4) + 255) / 256, 256, 0, stream>>>(cells, Cg, bh, outp);
}